// Round 11
// baseline (1025.277 us; speedup 1.0000x reference)
//
#include <hip/hip_runtime.h>
#include <hip/hip_bf16.h>
#include <math.h>

typedef __hip_bfloat16 bf16;
typedef __attribute__((ext_vector_type(8))) short short8;
typedef __attribute__((ext_vector_type(4))) float f32x4;

#define N_NODE 4096
#define DIM 200
#define NH 8
#define SEQ 4
#define TLDA 40
#define LDSB (64 * TLDA)   // shorts per LDS tile (5120 B)

__device__ __forceinline__ float eluf(float x) { return x > 0.f ? x : expm1f(x); }
__device__ __forceinline__ float sigm(float x) { return 1.f / (1.f + expf(-x)); }

template<bool ISB>
__device__ __forceinline__ float ldv(const void* p, size_t i) {
    if (ISB) return __bfloat162float(((const bf16*)p)[i]);
    else     return ((const float*)p)[i];
}
template<bool ISB>
__device__ __forceinline__ void stv(void* p, size_t i, float v) {
    if (ISB) ((bf16*)p)[i] = __float2bfloat16(v);
    else     ((float*)p)[i] = v;
}
__device__ __forceinline__ float bflo(unsigned u) { return __uint_as_float((u & 0xffffu) << 16); }
__device__ __forceinline__ float bfhi(unsigned u) { return __uint_as_float(u & 0xffff0000u); }
__device__ __forceinline__ short f2bs(float v) {
    bf16 h = __float2bfloat16(v);
    return *(short*)&h;
}

// Detect input dtype from feats (values ~ N(0,1)). See round-1/2 analysis.
__global__ void k_detect(const void* feats, int* flag) {
    __shared__ int cnt;
    if (threadIdx.x == 0) cnt = 0;
    __syncthreads();
    const unsigned short* u = (const unsigned short*)feats;
    unsigned short v = u[2 * threadIdx.x];
    int e = (v >> 7) & 0xFF;
    if (e >= 100 && e <= 140) atomicAdd(&cnt, 1);
    __syncthreads();
    if (threadIdx.x == 0) *flag = (cnt >= 128) ? 1 : 0;
}

// ---------------- MFMA GEMM core (verified rounds 8-10) ----------------
template<bool AISB>
__device__ __forceinline__ void ldA8(const void* A, int lda, int arow, bool rowOK,
                                     int kk, int K, float* la) {
    if (rowOK && kk + 8 <= K) {
        if (AISB) {
            const unsigned short* ap = (const unsigned short*)A + (size_t)arow * lda + kk;
            uint4 u = *(const uint4*)ap;
            la[0] = bflo(u.x); la[1] = bfhi(u.x);
            la[2] = bflo(u.y); la[3] = bfhi(u.y);
            la[4] = bflo(u.z); la[5] = bfhi(u.z);
            la[6] = bflo(u.w); la[7] = bfhi(u.w);
        } else {
            const float* ap = (const float*)A + (size_t)arow * lda + kk;
            float4 f0 = *(const float4*)ap;
            float4 f1 = *(const float4*)(ap + 4);
            la[0] = f0.x; la[1] = f0.y; la[2] = f0.z; la[3] = f0.w;
            la[4] = f1.x; la[5] = f1.y; la[6] = f1.z; la[7] = f1.w;
        }
    } else {
#pragma unroll
        for (int j = 0; j < 8; j++)
            la[j] = (rowOK && kk + j < K) ? ldv<AISB>(A, (size_t)arow * lda + kk + j) : 0.f;
    }
}
template<bool BISB>
__device__ __forceinline__ void ldB8(const void* B, int gcol, bool colOK,
                                     int kk, int K, float* lb) {
#pragma unroll
    for (int j = 0; j < 8; j++)
        lb[j] = (colOK && kk + j < K) ? ldv<BISB>(B, (size_t)(kk + j) * DIM + gcol) : 0.f;
}

// EPI 0: C=elu(acc+X1[col]); EPI 4: C[ci]=acc (partial store)
template<int EPI, bool AISB, bool BISB>
__device__ void mgemm(const void* A, int lda, const void* B, int M, int K,
                      int kbeg, int kend, const float* X1, float* C,
                      int row0, int c0, short* As, short* Bs) {
    const int N = DIM;
    int tid = threadIdx.x;
    int wave = tid >> 6, lane = tid & 63;
    int m16 = lane & 15, q = lane >> 4;
    int s_row = tid >> 2;
    int s_k   = (tid & 3) * 8;
    int b_col = tid & 63;
    int b_kg  = (tid >> 6) * 8;
    int arow = row0 + s_row;
    bool rowOK = arow < M;
    int gcol = c0 + b_col;
    bool colOK = gcol < N;
    float la[8], lb[8];
    ldA8<AISB>(A, lda, arow, rowOK, kbeg + s_k, K, la);
    ldB8<BISB>(B, gcol, colOK, kbeg + b_kg, K, lb);
    f32x4 acc[4] = {};
    for (int k0 = kbeg; k0 < kend; k0 += 32) {
        __syncthreads();
        short8 a8, b8;
#pragma unroll
        for (int j = 0; j < 8; j++) { a8[j] = f2bs(la[j]); b8[j] = f2bs(lb[j]); }
        *(short8*)&As[s_row * TLDA + s_k] = a8;
        *(short8*)&Bs[b_col * TLDA + b_kg] = b8;
        __syncthreads();
        int kn = k0 + 32;
        if (kn < kend) {
            ldA8<AISB>(A, lda, arow, rowOK, kn + s_k, K, la);
            ldB8<BISB>(B, gcol, colOK, kn + b_kg, K, lb);
        }
        short8 bf = *(short8*)&Bs[(wave * 16 + m16) * TLDA + q * 8];
#pragma unroll
        for (int r = 0; r < 4; r++) {
            short8 af = *(short8*)&As[(r * 16 + m16) * TLDA + q * 8];
            acc[r] = __builtin_amdgcn_mfma_f32_16x16x32_bf16(af, bf, acc[r], 0, 0, 0);
        }
    }
    int colw = c0 + wave * 16 + m16;
    if (colw >= N) return;
#pragma unroll
    for (int r = 0; r < 4; r++) {
        int rowb = row0 + r * 16 + q * 4;
#pragma unroll
        for (int reg = 0; reg < 4; reg++) {
            int row = rowb + reg;
            if (row >= M) continue;
            float v = acc[r][reg];
            size_t ci = (size_t)row * 200 + colw;
            if (EPI == 0) C[ci] = eluf(v + X1[colw]);
            else          C[ci] = v;
        }
    }
}

// ---------------- sparse A@W (verified round 7/8, standalone low-VGPR) ----
template<bool ISB>
__device__ void aw_body(const void* adjs, const unsigned short* Wcat, bf16* AWb,
                        int i, int s) {
    size_t arow = ((size_t)(s + 1) * N_NODE + i) * N_NODE;
    __shared__ int   s_k[512];
    __shared__ float s_v[512];
    __shared__ int   s_cnt;
    int tid = threadIdx.x;
    if (tid == 0) s_cnt = 0;
    __syncthreads();
    float vals[16];
#pragma unroll
    for (int c = 0; c < 4; c++) {
        int col = c * 1024 + tid * 4;
        if (ISB) {
            ushort4 u = *(const ushort4*)((const unsigned short*)adjs + arow + col);
            vals[c*4+0] = __uint_as_float((unsigned)u.x << 16);
            vals[c*4+1] = __uint_as_float((unsigned)u.y << 16);
            vals[c*4+2] = __uint_as_float((unsigned)u.z << 16);
            vals[c*4+3] = __uint_as_float((unsigned)u.w << 16);
        } else {
            float4 f = *(const float4*)((const float*)adjs + arow + col);
            vals[c*4+0] = f.x; vals[c*4+1] = f.y; vals[c*4+2] = f.z; vals[c*4+3] = f.w;
        }
    }
#pragma unroll
    for (int q = 0; q < 16; q++) {
        if (vals[q] != 0.f) {
            int p = atomicAdd(&s_cnt, 1);
            if (p < 512) { s_k[p] = (q >> 2) * 1024 + tid * 4 + (q & 3); s_v[p] = vals[q]; }
        }
    }
    __syncthreads();
    int n = s_cnt < 512 ? s_cnt : 512;
    float a0 = 0.f, a1 = 0.f, d0 = 0.f, d1 = 0.f;
    bool hasB = (tid < 44);
    int offA = 2 * tid, offB = 512 + 2 * tid;
    int e = 0;
    for (; e + 4 <= n; e += 4) {
        int   k0 = s_k[e],   k1 = s_k[e+1], k2 = s_k[e+2], k3 = s_k[e+3];
        float v0 = s_v[e],   v1 = s_v[e+1], v2 = s_v[e+2], v3 = s_v[e+3];
        unsigned wa0 = *(const unsigned*)(Wcat + (size_t)k0 * 608 + offA);
        unsigned wa1 = *(const unsigned*)(Wcat + (size_t)k1 * 608 + offA);
        unsigned wa2 = *(const unsigned*)(Wcat + (size_t)k2 * 608 + offA);
        unsigned wa3 = *(const unsigned*)(Wcat + (size_t)k3 * 608 + offA);
        if (hasB) {
            unsigned wb0 = *(const unsigned*)(Wcat + (size_t)k0 * 608 + offB);
            unsigned wb1 = *(const unsigned*)(Wcat + (size_t)k1 * 608 + offB);
            unsigned wb2 = *(const unsigned*)(Wcat + (size_t)k2 * 608 + offB);
            unsigned wb3 = *(const unsigned*)(Wcat + (size_t)k3 * 608 + offB);
            d0 += v0*bflo(wb0) + v1*bflo(wb1) + v2*bflo(wb2) + v3*bflo(wb3);
            d1 += v0*bfhi(wb0) + v1*bfhi(wb1) + v2*bfhi(wb2) + v3*bfhi(wb3);
        }
        a0 += v0*bflo(wa0) + v1*bflo(wa1) + v2*bflo(wa2) + v3*bflo(wa3);
        a1 += v0*bfhi(wa0) + v1*bfhi(wa1) + v2*bfhi(wa2) + v3*bfhi(wa3);
    }
    for (; e < n; e++) {
        int k = s_k[e]; float v = s_v[e];
        unsigned wa = *(const unsigned*)(Wcat + (size_t)k * 608 + offA);
        a0 += v * bflo(wa); a1 += v * bfhi(wa);
        if (hasB) {
            unsigned wb = *(const unsigned*)(Wcat + (size_t)k * 608 + offB);
            d0 += v * bflo(wb); d1 += v * bfhi(wb);
        }
    }
    int gA = (offA < 200) ? 0 : (offA < 400 ? 1 : 2);
    int oA = offA - gA * 200;
    size_t wbase = ((size_t)(s * 3 + gA) * N_NODE + i) * DIM + oA;
    AWb[wbase]     = __float2bfloat16(a0);
    AWb[wbase + 1] = __float2bfloat16(a1);
    if (hasB) {
        int oB = offB - 400;
        size_t wb2 = ((size_t)(s * 3 + 2) * N_NODE + i) * DIM + oB;
        AWb[wb2]     = __float2bfloat16(d0);
        AWb[wb2 + 1] = __float2bfloat16(d1);
    }
}
__global__ __launch_bounds__(256) void k_aw(const int* fl, const void* adjs,
        const unsigned short* Wcat, bf16* AWb) {
    int i = blockIdx.x & (N_NODE - 1), s = blockIdx.x >> 12;
    if (*fl) aw_body<true >(adjs, Wcat, AWb, i, s);
    else     aw_body<false>(adjs, Wcat, AWb, i, s);
}

// ---------------- fused: P@AW partials (1152) + GAT linear 1 (1024) -------
__global__ __launch_bounds__(256) void k_pg1(const int* fl,
        const void* P0, const void* P1, const void* P2, const bf16* AWb, float* Gp,
        const void* feats, const float* W1t, const float* b1f, float* Hbuf) {
    __shared__ short smem[2 * LDSB];
    int b = blockIdx.x;
    if (b < 1152) {
        int z = b >> 4, rem = b & 15;
        int row0 = (rem >> 2) * 64, c0 = (rem & 3) * 64;
        int sg = z >> 3, split = z & 7;
        int g = sg - (sg / 3) * 3;
        const void* A = (g == 0) ? P0 : (g == 1) ? P1 : P2;
        const void* B = AWb + (size_t)sg * N_NODE * DIM;
        float* C = Gp + (size_t)z * DIM * DIM;
        int kbeg = split * (N_NODE / 8), kend = kbeg + N_NODE / 8;
        if (*fl) mgemm<4, true , true>(A, N_NODE, B, DIM, N_NODE, kbeg, kend,
                                       nullptr, C, row0, c0, smem, smem + LDSB);
        else     mgemm<4, false, true>(A, N_NODE, B, DIM, N_NODE, kbeg, kend,
                                       nullptr, C, row0, c0, smem, smem + LDSB);
    } else {
        int t = b - 1152;
        int row0 = (t >> 2) * 64, c0 = (t & 3) * 64;
        if (*fl) mgemm<0, true , false>(feats, DIM, W1t, SEQ * N_NODE, DIM, 0, DIM,
                                        b1f, Hbuf, row0, c0, smem, smem + LDSB);
        else     mgemm<0, false, false>(feats, DIM, W1t, SEQ * N_NODE, DIM, 0, DIM,
                                        b1f, Hbuf, row0, c0, smem, smem + LDSB);
    }
}

// ---------------- fused: GAT linear 2 (1024) + G reduce (1407) ------------
__global__ __launch_bounds__(256) void k_pgr(const float* Hbuf, const float* W2t,
        const float* b2f, float* Obuf, const float* Gp, float* G) {
    __shared__ short smem[2 * LDSB];
    int b = blockIdx.x;
    if (b < 1024) {
        int row0 = (b >> 2) * 64, c0 = (b & 3) * 64;
        mgemm<0, false, false>(Hbuf, DIM, W2t, SEQ * N_NODE, DIM, 0, DIM,
                               b2f, Obuf, row0, c0, smem, smem + LDSB);
    } else {
        int rb = b - 1024;
        int idx = rb * 256 + threadIdx.x;
        if (idx < 9 * DIM * DIM) {
            int sg = idx / (DIM * DIM), r = idx - sg * (DIM * DIM);
            float s = 0.f;
#pragma unroll
            for (int sp = 0; sp < 8; sp++)
                s += Gp[(size_t)(sg * 8 + sp) * DIM * DIM + r];
            G[idx] += s;
        }
    }
}

// ---------------- row-local GRU chain (barrier-free across steps) ---------
// Block owns rows [blk*64, blk*64+64) of wv[1600][200]. All three GRU steps
// are row-local: wv@U row a depends only on wv row a; rw/u/update elementwise.
// rw is written into LDS directly in MFMA A-frag layout (stride 224 shorts,
// pad cols [200,224) zeroed once); u kept f32 in LDS; wv row-private global.
__device__ void chain_body(const int* fl, float* wv, const float* Utf,
                           const float* G, void* out, char* smem, int blk) {
    short* As  = (short*)smem;                  // 5120 B
    short* Bs1 = (short*)(smem + 5120);         // 5120 B
    short* Bs2 = (short*)(smem + 10240);        // 5120 B
    short* rwT = (short*)(smem + 15360);        // 64x224 shorts = 28672 B
    float* uT  = (float*)(smem + 44032);        // 64x200 f32 = 51200 B (end 95232)
    const int K = DIM, N = DIM;
    int r0 = blk * 64;
    int tid = threadIdx.x;
    int wave = tid >> 6, lane = tid & 63;
    int m16 = lane & 15, q = lane >> 4;
    int s_row = tid >> 2, s_k = (tid & 3) * 8;
    int b_col = tid & 63, b_kg = (tid >> 6) * 8;
    for (int idx = tid; idx < 64 * 24; idx += 256) {
        int r = idx / 24, k = 200 + idx % 24;
        rwT[r * 224 + k] = 0;
    }
    const float* Ur = Utf;
    const float* Uu = Utf + 40000;
    const float* Uh = Utf + 80000;
    for (int s = 0; s < 3; s++) {
        const float* Gr = G + (size_t)(s * 3 + 0) * 40000;
        const float* Gu = G + (size_t)(s * 3 + 1) * 40000;
        const float* Gh = G + (size_t)(s * 3 + 2) * 40000;
        // ---- e12: r & u gates, 4 col tiles ----
        for (int ct = 0; ct < 4; ct++) {
            int c0 = ct * 64;
            int arow = r0 + s_row;
            int gcol = c0 + b_col;
            bool colOK = gcol < N;
            float la[8], lbr[8], lbu[8];
            ldA8<false>(wv, K, arow, true, s_k, K, la);
            ldB8<false>(Ur, gcol, colOK, b_kg, K, lbr);
            ldB8<false>(Uu, gcol, colOK, b_kg, K, lbu);
            f32x4 accR[4] = {}, accU[4] = {};
            for (int k0 = 0; k0 < K; k0 += 32) {
                __syncthreads();
                short8 a8, r8, u8;
#pragma unroll
                for (int j = 0; j < 8; j++) {
                    a8[j] = f2bs(la[j]); r8[j] = f2bs(lbr[j]); u8[j] = f2bs(lbu[j]);
                }
                *(short8*)&As[s_row * TLDA + s_k] = a8;
                *(short8*)&Bs1[b_col * TLDA + b_kg] = r8;
                *(short8*)&Bs2[b_col * TLDA + b_kg] = u8;
                __syncthreads();
                int kn = k0 + 32;
                if (kn < K) {
                    ldA8<false>(wv, K, arow, true, kn + s_k, K, la);
                    ldB8<false>(Ur, gcol, colOK, kn + b_kg, K, lbr);
                    ldB8<false>(Uu, gcol, colOK, kn + b_kg, K, lbu);
                }
                short8 bfr = *(short8*)&Bs1[(wave * 16 + m16) * TLDA + q * 8];
                short8 bfu = *(short8*)&Bs2[(wave * 16 + m16) * TLDA + q * 8];
#pragma unroll
                for (int r = 0; r < 4; r++) {
                    short8 af = *(short8*)&As[(r * 16 + m16) * TLDA + q * 8];
                    accR[r] = __builtin_amdgcn_mfma_f32_16x16x32_bf16(af, bfr, accR[r], 0, 0, 0);
                    accU[r] = __builtin_amdgcn_mfma_f32_16x16x32_bf16(af, bfu, accU[r], 0, 0, 0);
                }
            }
            int colw = c0 + wave * 16 + m16;
            if (colw < N) {
#pragma unroll
                for (int r = 0; r < 4; r++) {
#pragma unroll
                    for (int reg = 0; reg < 4; reg++) {
                        int rl = r * 16 + q * 4 + reg;
                        int row = r0 + rl;
                        int a200 = row - (row / 200) * 200;
                        size_t ci = (size_t)row * 200 + colw;
                        float rv = sigm(Gr[a200 * 200 + colw] + accR[r][reg]);
                        float uu = sigm(Gu[a200 * 200 + colw] + accU[r][reg]);
                        rwT[rl * 224 + colw] = f2bs(rv * wv[ci]);
                        uT[rl * 200 + colw] = uu;
                    }
                }
            }
        }
        // ---- e3: hcap + wv update, 4 col tiles (A = rwT, no restaging) ----
        for (int ct = 0; ct < 4; ct++) {
            int c0 = ct * 64;
            int gcol = c0 + b_col;
            bool colOK = gcol < N;
            float lb[8];
            ldB8<false>(Uh, gcol, colOK, b_kg, K, lb);
            f32x4 acc[4] = {};
            for (int k0 = 0; k0 < K; k0 += 32) {
                __syncthreads();
                short8 b8;
#pragma unroll
                for (int j = 0; j < 8; j++) b8[j] = f2bs(lb[j]);
                *(short8*)&Bs1[b_col * TLDA + b_kg] = b8;
                __syncthreads();
                int kn = k0 + 32;
                if (kn < K) ldB8<false>(Uh, gcol, colOK, kn + b_kg, K, lb);
                short8 bf = *(short8*)&Bs1[(wave * 16 + m16) * TLDA + q * 8];
#pragma unroll
                for (int r = 0; r < 4; r++) {
                    short8 af = *(short8*)&rwT[(r * 16 + m16) * 224 + k0 + q * 8];
                    acc[r] = __builtin_amdgcn_mfma_f32_16x16x32_bf16(af, bf, acc[r], 0, 0, 0);
                }
            }
            int colw = c0 + wave * 16 + m16;
            if (colw < N) {
#pragma unroll
                for (int r = 0; r < 4; r++) {
#pragma unroll
                    for (int reg = 0; reg < 4; reg++) {
                        int rl = r * 16 + q * 4 + reg;
                        int row = r0 + rl;
                        int a200 = row - (row / 200) * 200;
                        size_t ci = (size_t)row * 200 + colw;
                        float uu = uT[rl * 200 + colw];
                        float hc = tanhf(Gh[a200 * 200 + colw] + acc[r][reg]);
                        float nv = (1.f - uu) * wv[ci] + uu * hc;
                        wv[ci] = nv;
                        if (s == 2) {
                            size_t oo = (size_t)SEQ * N_NODE * DIM + ci;
                            if (*fl) stv<true>(out, oo, nv);
                            else     stv<false>(out, oo, nv);
                        }
                    }
                }
            }
        }
        __syncthreads();   // wv writes visible to next step's A prefetch
    }
}

// softmax body (verified round 6), pointerized LDS
template<bool ISB>
__device__ void softmax_body(const float* O, void* out, int t, int i0,
                             float* tile, float* pm, float* ps,
                             float* sm_m, float* sm_inv) {
    const float* ob = O + (size_t)t * N_NODE * DIM;
    int tid = threadIdx.x;
    for (int idx = tid; idx < 200 * 64; idx += 256) {
        int j = idx >> 6, c = idx & 63;
        tile[j * 65 + c] = ob[(size_t)j * N_NODE + i0 + c];
    }
    __syncthreads();
    int g = tid >> 6, lane = tid & 63;
    int j0 = g * 50, j1 = j0 + 50;
    float mp = -1e30f;
    for (int j = j0; j < j1; j++) mp = fmaxf(mp, tile[j * 65 + lane]);
    pm[g * 64 + lane] = mp;
    __syncthreads();
    if (tid < 64)
        sm_m[tid] = fmaxf(fmaxf(pm[tid], pm[64 + tid]), fmaxf(pm[128 + tid], pm[192 + tid]));
    __syncthreads();
    float mv = sm_m[lane];
    float sp = 0.f;
    for (int j = j0; j < j1; j++) {
        float e = expf(tile[j * 65 + lane] - mv);
        tile[j * 65 + lane] = e;
        sp += e;
    }
    ps[g * 64 + lane] = sp;
    __syncthreads();
    if (tid < 64)
        sm_inv[tid] = 1.f / (ps[tid] + ps[64 + tid] + ps[128 + tid] + ps[192 + tid]);
    __syncthreads();
    size_t ob2 = ((size_t)t * N_NODE + i0) * DIM;
    for (int idx = tid; idx < 64 * 200; idx += 256) {
        int il = idx / 200, j = idx - il * 200;
        stv<ISB>(out, ob2 + (size_t)il * DIM + j, tile[j * 65 + il] * sm_inv[il]);
    }
}

// ---------------- tail: chain (25 blocks) + softmax (256 blocks) ----------
__global__ __launch_bounds__(256) void k_tail(const int* fl, float* wv,
        const float* Utf, const float* G, const float* Obuf, void* out) {
    __shared__ __align__(16) char smem[95232];
    int b = blockIdx.x;
    if (b < 25) {
        chain_body(fl, wv, Utf, G, out, smem, b);
    } else {
        int sb = b - 25;
        int tt = sb >> 6, i0 = (sb & 63) * 64;
        float* tile = (float*)smem;
        float* pm   = (float*)(smem + 52000);
        float* ps   = (float*)(smem + 53024);
        float* smm  = (float*)(smem + 54048);
        float* smi  = (float*)(smem + 54304);
        if (*fl) softmax_body<true >(Obuf, out, tt, i0, tile, pm, ps, smm, smi);
        else     softmax_body<false>(Obuf, out, tt, i0, tile, pm, ps, smm, smi);
    }
}

// ---------------- merged prep (verified round 7) ----------------
template<bool ISB>
__device__ void prep_body(const void* W1, const void* b1, const void* W2, const void* b2,
                          const void* Ur, const void* Uu, const void* Uh,
                          const void* br, const void* bu, const void* bh,
                          const void* iwv, const void* Wr, const void* Wu, const void* Wh,
                          float* W1t, float* W2t, float* b1f, float* b2f,
                          float* Utf, float* wv, float* G, unsigned short* Wcat) {
    int idx = blockIdx.x * 256 + threadIdx.x;
    if (idx < 40000) {
        int k = idx / 200, n = idx % 200;
        W1t[idx] = ldv<ISB>(W1, (size_t)n * 200 + k);
    } else if (idx < 80000) {
        int r = idx - 40000;
        int k = r / 200, n = r % 200;
        float s = 0.f;
        for (int h = 0; h < NH; h++) s += ldv<ISB>(W2, (size_t)n * 1600 + h * 200 + k);
        W2t[r] = s;
    } else if (idx < 80512) {
        int j = idx - 80000;
        if (j < 256)      b1f[j] = (j < 200) ? ldv<ISB>(b1, j) : 0.f;
        else              b2f[j - 256] = (j - 256 < 200) ? ldv<ISB>(b2, j - 256) : 0.f;
    } else if (idx < 200512) {
        int j = idx - 80512;
        int g = j / 40000, r = j - g * 40000;
        const void* U = (g == 0) ? Ur : (g == 1) ? Uu : Uh;
        Utf[j] = ldv<ISB>(U, r);
    } else if (idx < 520512) {
        wv[idx - 200512] = ldv<ISB>(iwv, idx - 200512);
    } else if (idx < 880512) {
        int j = idx - 520512;
        int sg = j / 40000, r = j - sg * 40000;
        int g = sg - (sg / 3) * 3;
        const void* bb = (g == 0) ? br : (g == 1) ? bu : bh;
        G[j] = ldv<ISB>(bb, r);
    } else {
        int j = idx - 880512;
        if (j < 4096 * 600) {
            int k = j / 600, c = j - k * 600;
            int g = (c < 200) ? 0 : (c < 400 ? 1 : 2);
            int o = c - g * 200;
            const void* W = (g == 0) ? Wr : (g == 1) ? Wu : Wh;
            bf16 v = __float2bfloat16(ldv<ISB>(W, (size_t)k * 200 + o));
            Wcat[(size_t)k * 608 + c] = *(unsigned short*)&v;
        }
    }
}
__global__ void k_prep(const int* fl, const void* W1, const void* b1, const void* W2,
                       const void* b2, const void* Ur, const void* Uu, const void* Uh,
                       const void* br, const void* bu, const void* bh, const void* iwv,
                       const void* Wr, const void* Wu, const void* Wh,
                       float* W1t, float* W2t, float* b1f, float* b2f,
                       float* Utf, float* wv, float* G, unsigned short* Wcat) {
    if (*fl) prep_body<true >(W1, b1, W2, b2, Ur, Uu, Uh, br, bu, bh, iwv, Wr, Wu, Wh,
                              W1t, W2t, b1f, b2f, Utf, wv, G, Wcat);
    else     prep_body<false>(W1, b1, W2, b2, Ur, Uu, Uh, br, bu, bh, iwv, Wr, Wu, Wh,
                              W1t, W2t, b1f, b2f, Utf, wv, G, Wcat);
}

extern "C" void kernel_launch(void* const* d_in, const int* in_sizes, int n_in,
                              void* d_out, int out_size, void* d_ws, size_t ws_size,
                              hipStream_t stream) {
    const void* adjs    = d_in[0];
    const void* feats   = d_in[1];
    const void* init_wv = d_in[3];
    const void* W1 = d_in[4];
    const void* b1 = d_in[5];
    const void* W2 = d_in[10];
    const void* b2 = d_in[11];
    const void* Wr = d_in[16];
    const void* Ur = d_in[17];
    const void* Pr = d_in[18];
    const void* br = d_in[19];
    const void* Wu = d_in[20];
    const void* Uu = d_in[21];
    const void* Pu = d_in[22];
    const void* bu = d_in[23];
    const void* Wh = d_in[24];
    const void* Uh = d_in[25];
    const void* Ph = d_in[26];
    const void* bh = d_in[27];

    // ---- workspace (floats): flat layout ----
    int*   flag = (int*)d_ws;
    float* base = (float*)d_ws;
    unsigned short* Wcat = (unsigned short*)(base + 64);   // 1,245,184 f
    bf16*  AWb  = (bf16*)(base + 1245248);                 // 3,686,400 f
    float* Hbuf = base + 4931648;         // 3,276,800
    float* Obuf = Hbuf + 3276800;         // 3,276,800
    float* W1t  = base + 11485248;        // 40,000
    float* W2t  = W1t + 40000;            // 40,000
    float* b1f  = W2t + 40000;            // 256
    float* b2f  = b1f + 256;              // 256
    float* Utf  = b2f + 256;              // 120,000
    float* G    = Utf + 120000;           // 360,000
    float* wv   = G + 360000;             // 320,000
    float* Gp   = wv + 320000;            // 2,880,000 (total ~61 MB)

    k_detect<<<1, 256, 0, stream>>>(feats, flag);
    k_prep<<<(3338112 + 255) / 256, 256, 0, stream>>>(
        flag, W1, b1, W2, b2, Ur, Uu, Uh, br, bu, bh, init_wv, Wr, Wu, Wh,
        W1t, W2t, b1f, b2f, Utf, wv, G, Wcat);

    // sparse A@W (standalone, low VGPR for occupancy)
    k_aw<<<12288, 256, 0, stream>>>(flag, adjs, Wcat, AWb);
    // P@AW K-split partials (1152) || GAT linear 1 (1024)
    k_pg1<<<2176, 256, 0, stream>>>(flag, Pr, Pu, Ph, AWb, Gp, feats, W1t, b1f, Hbuf);
    // GAT linear 2 (1024) || G reduce (1407)
    k_pgr<<<2431, 256, 0, stream>>>(Hbuf, W2t, b2f, Obuf, Gp, G);
    // row-local GRU chain (25 blocks, barrier-free) || softmax (256 blocks)
    k_tail<<<281, 256, 0, stream>>>(flag, wv, Utf, G, Obuf, d_out);
}

// Round 12
// 674.190 us; speedup vs baseline: 1.5208x; 1.5208x over previous
//
#include <hip/hip_runtime.h>
#include <hip/hip_bf16.h>
#include <math.h>

typedef __hip_bfloat16 bf16;
typedef __attribute__((ext_vector_type(8))) short short8;
typedef __attribute__((ext_vector_type(4))) float f32x4;

#define N_NODE 4096
#define DIM 200
#define NH 8
#define SEQ 4
#define TLDA 40   // LDS tile row stride in shorts (80 B: 16B-aligned frags, 2-way banks)

__device__ __forceinline__ float eluf(float x) { return x > 0.f ? x : expm1f(x); }
__device__ __forceinline__ float sigm(float x) { return 1.f / (1.f + expf(-x)); }

template<bool ISB>
__device__ __forceinline__ float ldv(const void* p, size_t i) {
    if (ISB) return __bfloat162float(((const bf16*)p)[i]);
    else     return ((const float*)p)[i];
}
template<bool ISB>
__device__ __forceinline__ void stv(void* p, size_t i, float v) {
    if (ISB) ((bf16*)p)[i] = __float2bfloat16(v);
    else     ((float*)p)[i] = v;
}
__device__ __forceinline__ float bflo(unsigned u) { return __uint_as_float((u & 0xffffu) << 16); }
__device__ __forceinline__ float bfhi(unsigned u) { return __uint_as_float(u & 0xffff0000u); }
__device__ __forceinline__ short f2bs(float v) {
    bf16 h = __float2bfloat16(v);
    return *(short*)&h;
}

// Detect input dtype from feats (values ~ N(0,1)). See round-1/2 analysis.
__global__ void k_detect(const void* feats, int* flag) {
    __shared__ int cnt;
    if (threadIdx.x == 0) cnt = 0;
    __syncthreads();
    const unsigned short* u = (const unsigned short*)feats;
    unsigned short v = u[2 * threadIdx.x];
    int e = (v >> 7) & 0xFF;
    if (e >= 100 && e <= 140) atomicAdd(&cnt, 1);
    __syncthreads();
    if (threadIdx.x == 0) *flag = (cnt >= 128) ? 1 : 0;
}

// ---------------- MFMA GEMM core (verified round 8) ----------------
// Block = 256 thr = 4 waves. C-tile 64x64; wave w -> cols [w*16,w*16+16),
// rows 0..63 (4 row-frags). K-chunk 32 staged to LDS bf16, k-contiguous:
// As[row][k] / Bs[col][k], stride TLDA. Fragments (HW-verified gfx950):
// A: m=lane&15, k=quad*8+j; B: n=lane&15, k=quad*8+j; D: col=lane&15,
// row=quad*4+reg. Reg-prefetch pipeline.
// EPI 0: C=elu(acc+X1[col]); EPI 3: GRU wv update (+opt fused out2 copy);
// EPI 4: atomicAdd(C, acc) (K-split, C pre-init with bias).

template<bool AISB>
__device__ __forceinline__ void ldA8(const void* A, int lda, int arow, bool rowOK,
                                     int kk, int K, float* la) {
    if (rowOK && kk + 8 <= K) {
        if (AISB) {
            const unsigned short* ap = (const unsigned short*)A + (size_t)arow * lda + kk;
            uint4 u = *(const uint4*)ap;
            la[0] = bflo(u.x); la[1] = bfhi(u.x);
            la[2] = bflo(u.y); la[3] = bfhi(u.y);
            la[4] = bflo(u.z); la[5] = bfhi(u.z);
            la[6] = bflo(u.w); la[7] = bfhi(u.w);
        } else {
            const float* ap = (const float*)A + (size_t)arow * lda + kk;
            float4 f0 = *(const float4*)ap;
            float4 f1 = *(const float4*)(ap + 4);
            la[0] = f0.x; la[1] = f0.y; la[2] = f0.z; la[3] = f0.w;
            la[4] = f1.x; la[5] = f1.y; la[6] = f1.z; la[7] = f1.w;
        }
    } else {
#pragma unroll
        for (int j = 0; j < 8; j++)
            la[j] = (rowOK && kk + j < K) ? ldv<AISB>(A, (size_t)arow * lda + kk + j) : 0.f;
    }
}
template<bool BISB>
__device__ __forceinline__ void ldB8(const void* B, int gcol, bool colOK,
                                     int kk, int K, float* lb) {
#pragma unroll
    for (int j = 0; j < 8; j++)
        lb[j] = (colOK && kk + j < K) ? ldv<BISB>(B, (size_t)(kk + j) * DIM + gcol) : 0.f;
}

template<int EPI, bool AISB, bool BISB>
__device__ void mgemm(const void* A, int lda, const void* B, int M, int K,
                      int kbeg, int kend, const float* X1, const float* X2,
                      float* C, int row0, int c0, const int* fl, void* out2) {
    const int N = DIM;
    int tid = threadIdx.x;
    int wave = tid >> 6, lane = tid & 63;
    int m16 = lane & 15, q = lane >> 4;
    __shared__ short As[64 * TLDA];
    __shared__ short Bs[64 * TLDA];
    int s_row = tid >> 2;
    int s_k   = (tid & 3) * 8;
    int b_col = tid & 63;
    int b_kg  = (tid >> 6) * 8;
    int arow = row0 + s_row;
    bool rowOK = arow < M;
    int gcol = c0 + b_col;
    bool colOK = gcol < N;
    float la[8], lb[8];
    ldA8<AISB>(A, lda, arow, rowOK, kbeg + s_k, K, la);
    ldB8<BISB>(B, gcol, colOK, kbeg + b_kg, K, lb);
    f32x4 acc[4] = {};
    for (int k0 = kbeg; k0 < kend; k0 += 32) {
        __syncthreads();
        short8 a8, b8;
#pragma unroll
        for (int j = 0; j < 8; j++) { a8[j] = f2bs(la[j]); b8[j] = f2bs(lb[j]); }
        *(short8*)&As[s_row * TLDA + s_k] = a8;
        *(short8*)&Bs[b_col * TLDA + b_kg] = b8;
        __syncthreads();
        int kn = k0 + 32;
        if (kn < kend) {
            ldA8<AISB>(A, lda, arow, rowOK, kn + s_k, K, la);
            ldB8<BISB>(B, gcol, colOK, kn + b_kg, K, lb);
        }
        short8 bf = *(short8*)&Bs[(wave * 16 + m16) * TLDA + q * 8];
#pragma unroll
        for (int r = 0; r < 4; r++) {
            short8 af = *(short8*)&As[(r * 16 + m16) * TLDA + q * 8];
            acc[r] = __builtin_amdgcn_mfma_f32_16x16x32_bf16(af, bf, acc[r], 0, 0, 0);
        }
    }
    int colw = c0 + wave * 16 + m16;
    if (colw >= N) return;
#pragma unroll
    for (int r = 0; r < 4; r++) {
        int rowb = row0 + r * 16 + q * 4;
#pragma unroll
        for (int reg = 0; reg < 4; reg++) {
            int row = rowb + reg;
            if (row >= M) continue;
            float v = acc[r][reg];
            size_t ci = (size_t)row * 200 + colw;
            if (EPI == 0) {
                C[ci] = eluf(v + X1[colw]);
            } else if (EPI == 3) {
                int a200 = row - (row / 200) * 200;
                float uu = X2[ci];
                float hc = tanhf(X1[a200 * 200 + colw] + v);
                float nv = (1.f - uu) * C[ci] + uu * hc;
                C[ci] = nv;
                if (out2) {
                    size_t oo = (size_t)SEQ * N_NODE * DIM + ci;
                    if (*fl) stv<true>(out2, oo, nv); else stv<false>(out2, oo, nv);
                }
            } else {
                atomicAdd(&C[ci], v);
            }
        }
    }
}

// dual-B (r+u gate) MFMA GEMM: A=wv [1600x200] f32, Br=Ur, Bu=Uu f32.
__global__ __launch_bounds__(256) void k_gemm_e12(const float* A,
        const float* Br, const float* Bu, const float* Gr, const float* Gu,
        float* rw, float* u) {
    const int M = NH * DIM, K = DIM, N = DIM;
    int row0 = blockIdx.y * 64, c0 = blockIdx.x * 64;
    int tid = threadIdx.x;
    int wave = tid >> 6, lane = tid & 63;
    int m16 = lane & 15, q = lane >> 4;
    __shared__ short As[64 * TLDA];
    __shared__ short Bsr[64 * TLDA];
    __shared__ short Bsu[64 * TLDA];
    int s_row = tid >> 2;
    int s_k   = (tid & 3) * 8;
    int b_col = tid & 63;
    int b_kg  = (tid >> 6) * 8;
    int arow = row0 + s_row;
    bool rowOK = arow < M;
    int gcol = c0 + b_col;
    bool colOK = gcol < N;
    float la[8], lbr[8], lbu[8];
    ldA8<false>(A, K, arow, rowOK, s_k, K, la);
    ldB8<false>(Br, gcol, colOK, b_kg, K, lbr);
    ldB8<false>(Bu, gcol, colOK, b_kg, K, lbu);
    f32x4 accR[4] = {}, accU[4] = {};
    for (int k0 = 0; k0 < K; k0 += 32) {
        __syncthreads();
        short8 a8, r8, u8;
#pragma unroll
        for (int j = 0; j < 8; j++) {
            a8[j] = f2bs(la[j]); r8[j] = f2bs(lbr[j]); u8[j] = f2bs(lbu[j]);
        }
        *(short8*)&As[s_row * TLDA + s_k] = a8;
        *(short8*)&Bsr[b_col * TLDA + b_kg] = r8;
        *(short8*)&Bsu[b_col * TLDA + b_kg] = u8;
        __syncthreads();
        int kn = k0 + 32;
        if (kn < K) {
            ldA8<false>(A, K, arow, rowOK, kn + s_k, K, la);
            ldB8<false>(Br, gcol, colOK, kn + b_kg, K, lbr);
            ldB8<false>(Bu, gcol, colOK, kn + b_kg, K, lbu);
        }
        short8 bfr = *(short8*)&Bsr[(wave * 16 + m16) * TLDA + q * 8];
        short8 bfu = *(short8*)&Bsu[(wave * 16 + m16) * TLDA + q * 8];
#pragma unroll
        for (int r = 0; r < 4; r++) {
            short8 af = *(short8*)&As[(r * 16 + m16) * TLDA + q * 8];
            accR[r] = __builtin_amdgcn_mfma_f32_16x16x32_bf16(af, bfr, accR[r], 0, 0, 0);
            accU[r] = __builtin_amdgcn_mfma_f32_16x16x32_bf16(af, bfu, accU[r], 0, 0, 0);
        }
    }
    int colw = c0 + wave * 16 + m16;
    if (colw >= N) return;
#pragma unroll
    for (int r = 0; r < 4; r++) {
        int rowb = row0 + r * 16 + q * 4;
#pragma unroll
        for (int reg = 0; reg < 4; reg++) {
            int row = rowb + reg;
            if (row >= M) continue;
            int a200 = row - (row / 200) * 200;
            size_t ci = (size_t)row * 200 + colw;
            rw[ci] = sigm(Gr[a200 * 200 + colw] + accR[r][reg]) * A[ci];
            u[ci]  = sigm(Gu[a200 * 200 + colw] + accU[r][reg]);
        }
    }
}

__global__ __launch_bounds__(256) void k_gemm_e0(const int* fl, int useIsb,
        const void* A, int lda, const float* B, int M, int K,
        const float* bias, float* C) {
    int row0 = blockIdx.y * 64, c0 = blockIdx.x * 64;
    if (useIsb && *fl)
        mgemm<0, true , false>(A, lda, B, M, K, 0, K, bias, nullptr, C, row0, c0, nullptr, nullptr);
    else
        mgemm<0, false, false>(A, lda, B, M, K, 0, K, bias, nullptr, C, row0, c0, nullptr, nullptr);
}
__global__ __launch_bounds__(256) void k_gemm_e3(const float* A, const float* B,
        const float* G0, const float* U, float* WV, const int* fl, void* out2) {
    mgemm<3, false, false>(A, DIM, B, NH * DIM, DIM, 0, DIM, G0, U, WV,
                           blockIdx.y * 64, blockIdx.x * 64, fl, out2);
}
// K-split P@AW (AW bf16): z = sg*8 + split; atomicAdd into bias-init G
__global__ __launch_bounds__(256) void k_pggemm(const int* fl,
        const void* P0, const void* P1, const void* P2,
        const bf16* AWb, float* G) {
    int z = blockIdx.z;
    int sg = z >> 3, split = z & 7;
    int g = sg - (sg / 3) * 3;
    const void* A = (g == 0) ? P0 : (g == 1) ? P1 : P2;
    const void* B = AWb + (size_t)sg * N_NODE * DIM;
    float* C = G + (size_t)sg * DIM * DIM;
    int row0 = blockIdx.y * 64, c0 = blockIdx.x * 64;
    int kbeg = split * (N_NODE / 8), kend = kbeg + N_NODE / 8;
    if (*fl) mgemm<4, true , true>(A, N_NODE, B, DIM, N_NODE, kbeg, kend, nullptr, nullptr, C, row0, c0, nullptr, nullptr);
    else     mgemm<4, false, true>(A, N_NODE, B, DIM, N_NODE, kbeg, kend, nullptr, nullptr, C, row0, c0, nullptr, nullptr);
}

// ---------------- merged prep (verified round 7) ----------------
template<bool ISB>
__device__ void prep_body(const void* W1, const void* b1, const void* W2, const void* b2,
                          const void* Ur, const void* Uu, const void* Uh,
                          const void* br, const void* bu, const void* bh,
                          const void* iwv, const void* Wr, const void* Wu, const void* Wh,
                          float* W1t, float* W2t, float* b1f, float* b2f,
                          float* Utf, float* wv, float* G, unsigned short* Wcat) {
    int idx = blockIdx.x * 256 + threadIdx.x;
    if (idx < 40000) {
        int k = idx / 200, n = idx % 200;
        W1t[idx] = ldv<ISB>(W1, (size_t)n * 200 + k);
    } else if (idx < 80000) {
        int r = idx - 40000;
        int k = r / 200, n = r % 200;
        float s = 0.f;
        for (int h = 0; h < NH; h++) s += ldv<ISB>(W2, (size_t)n * 1600 + h * 200 + k);
        W2t[r] = s;
    } else if (idx < 80512) {
        int j = idx - 80000;
        if (j < 256)      b1f[j] = (j < 200) ? ldv<ISB>(b1, j) : 0.f;
        else              b2f[j - 256] = (j - 256 < 200) ? ldv<ISB>(b2, j - 256) : 0.f;
    } else if (idx < 200512) {
        int j = idx - 80512;
        int g = j / 40000, r = j - g * 40000;
        const void* U = (g == 0) ? Ur : (g == 1) ? Uu : Uh;
        Utf[j] = ldv<ISB>(U, r);
    } else if (idx < 520512) {
        wv[idx - 200512] = ldv<ISB>(iwv, idx - 200512);
    } else if (idx < 880512) {
        int j = idx - 520512;
        int sg = j / 40000, r = j - sg * 40000;
        int g = sg - (sg / 3) * 3;
        const void* bb = (g == 0) ? br : (g == 1) ? bu : bh;
        G[j] = ldv<ISB>(bb, r);
    } else {
        int j = idx - 880512;
        if (j < 4096 * 600) {
            int k = j / 600, c = j - k * 600;
            int g = (c < 200) ? 0 : (c < 400 ? 1 : 2);
            int o = c - g * 200;
            const void* W = (g == 0) ? Wr : (g == 1) ? Wu : Wh;
            bf16 v = __float2bfloat16(ldv<ISB>(W, (size_t)k * 200 + o));
            Wcat[(size_t)k * 608 + c] = *(unsigned short*)&v;
        }
    }
}
__global__ void k_prep(const int* fl, const void* W1, const void* b1, const void* W2,
                       const void* b2, const void* Ur, const void* Uu, const void* Uh,
                       const void* br, const void* bu, const void* bh, const void* iwv,
                       const void* Wr, const void* Wu, const void* Wh,
                       float* W1t, float* W2t, float* b1f, float* b2f,
                       float* Utf, float* wv, float* G, unsigned short* Wcat) {
    if (*fl) prep_body<true >(W1, b1, W2, b2, Ur, Uu, Uh, br, bu, bh, iwv, Wr, Wu, Wh,
                              W1t, W2t, b1f, b2f, Utf, wv, G, Wcat);
    else     prep_body<false>(W1, b1, W2, b2, Ur, Uu, Uh, br, bu, bh, iwv, Wr, Wu, Wh,
                              W1t, W2t, b1f, b2f, Utf, wv, G, Wcat);
}

// ---------------- softmax (verified round 6) ----------------
template<bool ISB>
__device__ void softmax_body(const float* O, void* out) {
    __shared__ float tile[200 * 65];
    __shared__ float pm[4 * 64];
    __shared__ float ps[4 * 64];
    __shared__ float sm_m[64];
    __shared__ float sm_inv[64];
    int t = blockIdx.y;
    int i0 = blockIdx.x * 64;
    const float* ob = O + (size_t)t * N_NODE * DIM;
    int tid = threadIdx.x;
    for (int idx = tid; idx < 200 * 64; idx += 256) {
        int j = idx >> 6, c = idx & 63;
        tile[j * 65 + c] = ob[(size_t)j * N_NODE + i0 + c];
    }
    __syncthreads();
    int g = tid >> 6, lane = tid & 63;
    int j0 = g * 50, j1 = j0 + 50;
    float mp = -1e30f;
    for (int j = j0; j < j1; j++) mp = fmaxf(mp, tile[j * 65 + lane]);
    pm[g * 64 + lane] = mp;
    __syncthreads();
    if (tid < 64)
        sm_m[tid] = fmaxf(fmaxf(pm[tid], pm[64 + tid]), fmaxf(pm[128 + tid], pm[192 + tid]));
    __syncthreads();
    float mv = sm_m[lane];
    float sp = 0.f;
    for (int j = j0; j < j1; j++) {
        float e = expf(tile[j * 65 + lane] - mv);
        tile[j * 65 + lane] = e;
        sp += e;
    }
    ps[g * 64 + lane] = sp;
    __syncthreads();
    if (tid < 64)
        sm_inv[tid] = 1.f / (ps[tid] + ps[64 + tid] + ps[128 + tid] + ps[192 + tid]);
    __syncthreads();
    size_t ob2 = ((size_t)t * N_NODE + i0) * DIM;
    for (int idx = tid; idx < 64 * 200; idx += 256) {
        int il = idx / 200, j = idx - il * 200;
        stv<ISB>(out, ob2 + (size_t)il * DIM + j, tile[j * 65 + il] * sm_inv[il]);
    }
}
__global__ __launch_bounds__(256) void k_softmax(const int* fl, const float* O, void* out) {
    if (*fl) softmax_body<true>(O, out); else softmax_body<false>(O, out);
}

// ---------------- sparse A@W (verified round 7) ----------------
template<bool ISB>
__device__ void aw_body(const void* adjs, const unsigned short* Wcat, bf16* AWb) {
    int i = blockIdx.x;
    int s = blockIdx.y;
    size_t arow = ((size_t)(s + 1) * N_NODE + i) * N_NODE;
    __shared__ int   s_k[512];
    __shared__ float s_v[512];
    __shared__ int   s_cnt;
    int tid = threadIdx.x;
    if (tid == 0) s_cnt = 0;
    __syncthreads();
    float vals[16];
#pragma unroll
    for (int c = 0; c < 4; c++) {
        int col = c * 1024 + tid * 4;
        if (ISB) {
            ushort4 u = *(const ushort4*)((const unsigned short*)adjs + arow + col);
            vals[c*4+0] = __uint_as_float((unsigned)u.x << 16);
            vals[c*4+1] = __uint_as_float((unsigned)u.y << 16);
            vals[c*4+2] = __uint_as_float((unsigned)u.z << 16);
            vals[c*4+3] = __uint_as_float((unsigned)u.w << 16);
        } else {
            float4 f = *(const float4*)((const float*)adjs + arow + col);
            vals[c*4+0] = f.x; vals[c*4+1] = f.y; vals[c*4+2] = f.z; vals[c*4+3] = f.w;
        }
    }
#pragma unroll
    for (int q = 0; q < 16; q++) {
        if (vals[q] != 0.f) {
            int p = atomicAdd(&s_cnt, 1);
            if (p < 512) { s_k[p] = (q >> 2) * 1024 + tid * 4 + (q & 3); s_v[p] = vals[q]; }
        }
    }
    __syncthreads();
    int n = s_cnt < 512 ? s_cnt : 512;
    float a0 = 0.f, a1 = 0.f, d0 = 0.f, d1 = 0.f;
    bool hasB = (tid < 44);
    int offA = 2 * tid, offB = 512 + 2 * tid;
    int e = 0;
    for (; e + 4 <= n; e += 4) {
        int   k0 = s_k[e],   k1 = s_k[e+1], k2 = s_k[e+2], k3 = s_k[e+3];
        float v0 = s_v[e],   v1 = s_v[e+1], v2 = s_v[e+2], v3 = s_v[e+3];
        unsigned wa0 = *(const unsigned*)(Wcat + (size_t)k0 * 608 + offA);
        unsigned wa1 = *(const unsigned*)(Wcat + (size_t)k1 * 608 + offA);
        unsigned wa2 = *(const unsigned*)(Wcat + (size_t)k2 * 608 + offA);
        unsigned wa3 = *(const unsigned*)(Wcat + (size_t)k3 * 608 + offA);
        if (hasB) {
            unsigned wb0 = *(const unsigned*)(Wcat + (size_t)k0 * 608 + offB);
            unsigned wb1 = *(const unsigned*)(Wcat + (size_t)k1 * 608 + offB);
            unsigned wb2 = *(const unsigned*)(Wcat + (size_t)k2 * 608 + offB);
            unsigned wb3 = *(const unsigned*)(Wcat + (size_t)k3 * 608 + offB);
            d0 += v0*bflo(wb0) + v1*bflo(wb1) + v2*bflo(wb2) + v3*bflo(wb3);
            d1 += v0*bfhi(wb0) + v1*bfhi(wb1) + v2*bfhi(wb2) + v3*bfhi(wb3);
        }
        a0 += v0*bflo(wa0) + v1*bflo(wa1) + v2*bflo(wa2) + v3*bflo(wa3);
        a1 += v0*bfhi(wa0) + v1*bfhi(wa1) + v2*bfhi(wa2) + v3*bfhi(wa3);
    }
    for (; e < n; e++) {
        int k = s_k[e]; float v = s_v[e];
        unsigned wa = *(const unsigned*)(Wcat + (size_t)k * 608 + offA);
        a0 += v * bflo(wa); a1 += v * bfhi(wa);
        if (hasB) {
            unsigned wb = *(const unsigned*)(Wcat + (size_t)k * 608 + offB);
            d0 += v * bflo(wb); d1 += v * bfhi(wb);
        }
    }
    int gA = (offA < 200) ? 0 : (offA < 400 ? 1 : 2);
    int oA = offA - gA * 200;
    size_t wbase = ((size_t)(s * 3 + gA) * N_NODE + i) * DIM + oA;
    AWb[wbase]     = __float2bfloat16(a0);
    AWb[wbase + 1] = __float2bfloat16(a1);
    if (hasB) {
        int oB = offB - 400;
        size_t wb2 = ((size_t)(s * 3 + 2) * N_NODE + i) * DIM + oB;
        AWb[wb2]     = __float2bfloat16(d0);
        AWb[wb2 + 1] = __float2bfloat16(d1);
    }
}
__global__ __launch_bounds__(256) void k_aw(const int* fl, const void* adjs,
        const unsigned short* Wcat, bf16* AWb) {
    if (*fl) aw_body<true>(adjs, Wcat, AWb);
    else     aw_body<false>(adjs, Wcat, AWb);
}

extern "C" void kernel_launch(void* const* d_in, const int* in_sizes, int n_in,
                              void* d_out, int out_size, void* d_ws, size_t ws_size,
                              hipStream_t stream) {
    const void* adjs    = d_in[0];
    const void* feats   = d_in[1];
    const void* init_wv = d_in[3];
    const void* W1 = d_in[4];
    const void* b1 = d_in[5];
    const void* W2 = d_in[10];
    const void* b2 = d_in[11];
    const void* Wr = d_in[16];
    const void* Ur = d_in[17];
    const void* Pr = d_in[18];
    const void* br = d_in[19];
    const void* Wu = d_in[20];
    const void* Uu = d_in[21];
    const void* Pu = d_in[22];
    const void* bu = d_in[23];
    const void* Wh = d_in[24];
    const void* Uh = d_in[25];
    const void* Ph = d_in[26];
    const void* bh = d_in[27];

    // ---- workspace (floats), phase overlay (round-7 layout) ----
    int*   flag = (int*)d_ws;
    float* base = (float*)d_ws;
    unsigned short* Wcat = (unsigned short*)(base + 64);        // 4096x608 bf16
    bf16*  AWb  = (bf16*)(base + 64 + 1245184);                 // 9x4096x200 bf16
    float* Hbuf = base + 64;
    float* Obuf = Hbuf + 3276800;
    float* W1t  = base + 6553664;
    float* W2t  = W1t + 40000;
    float* b1f  = W2t + 40000;
    float* b2f  = b1f + 256;
    float* ubuf = b2f + 256;
    float* rwbuf= ubuf + 320000;
    float* Utf  = rwbuf + 320000;
    float* G    = Utf + 120000;
    float* wv   = G + 360000;

    const int M = SEQ * N_NODE;           // 16384

    k_detect<<<1, 256, 0, stream>>>(feats, flag);
    k_prep<<<(3338112 + 255) / 256, 256, 0, stream>>>(
        flag, W1, b1, W2, b2, Ur, Uu, Uh, br, bu, bh, init_wv, Wr, Wu, Wh,
        W1t, W2t, b1f, b2f, Utf, wv, G, Wcat);

    // ---- GRU front half (overlay phase A) ----
    {
        dim3 g(N_NODE, 3);
        k_aw<<<g, 256, 0, stream>>>(flag, adjs, Wcat, AWb);
    }
    {
        dim3 g(4, 4, 72);
        k_pggemm<<<g, 256, 0, stream>>>(flag, Pr, Pu, Ph, AWb, G);
    }

    // ---- GAT branch (overlay phase B) ----
    {
        dim3 g(4, M / 64);
        k_gemm_e0<<<g, 256, 0, stream>>>(flag, 1, feats, DIM, W1t, M, DIM, b1f, Hbuf);
        k_gemm_e0<<<g, 256, 0, stream>>>(flag, 0, Hbuf, DIM, W2t, M, DIM, b2f, Obuf);
    }
    {
        dim3 g(N_NODE / 64, SEQ);
        k_softmax<<<g, 256, 0, stream>>>(flag, Obuf, d_out);
    }

    // ---- GRU chain ----
    {
        dim3 g(4, NH * DIM / 64);   // (4, 25)
        for (int s = 0; s < 3; s++) {
            const float* Gr = G + (size_t)(s * 3 + 0) * DIM * DIM;
            const float* Gu = G + (size_t)(s * 3 + 1) * DIM * DIM;
            const float* Gh = G + (size_t)(s * 3 + 2) * DIM * DIM;
            void* out2 = (s == 2) ? d_out : nullptr;
            k_gemm_e12<<<g, 256, 0, stream>>>(wv, Utf + 0, Utf + 40000, Gr, Gu, rwbuf, ubuf);
            k_gemm_e3<<<g, 256, 0, stream>>>(rwbuf, Utf + 80000, Gh, ubuf, wv, flag, out2);
        }
    }
}